// Round 1
// baseline (197.664 us; speedup 1.0000x reference)
//
#include <hip/hip_runtime.h>
#include <hip/hip_bf16.h>

// FenwickLogLinearAttention: B=2,T=2048,C=1024,H=16,Dh=64
// Pipeline: cvt(x)->bf16 ; W_qkv,W_proj -> transposed bf16 ([N][K]) ;
//           m97-style 128x128 MFMA GEMM (qkv, bf16 out) ;
//           sparse Fenwick attention (<=12 keys/query, wave per (b,h,t)) ;
//           m97-style GEMM (proj, fp32 out + bias) -> d_out.
// ws layout (bytes): xb@0 (8M) | WqkvT@8M (6M) | QKVb@14M (24M) | AO@38M (8M) | WprojT@46M (2M)

typedef unsigned short ushort_t;
typedef __attribute__((ext_vector_type(8))) short s16x8;
typedef __attribute__((ext_vector_type(4))) float f32x4;

#define T_SEQ 2048
#define C_DIM 1024
#define HEADS 16

__device__ __forceinline__ ushort_t f2bf(float f) {
    union { float f; unsigned u; } v{f};
    unsigned r = v.u + 0x7FFFu + ((v.u >> 16) & 1u);   // RNE
    return (ushort_t)(r >> 16);
}
__device__ __forceinline__ float bf2f(ushort_t u) {
    union { unsigned u; float f; } v{((unsigned)u) << 16};
    return v.f;
}

__device__ __forceinline__ void async16(const ushort_t* g, ushort_t* l) {
    __builtin_amdgcn_global_load_lds(
        (const __attribute__((address_space(1))) void*)g,
        (__attribute__((address_space(3))) void*)l, 16, 0, 0);
}

// ---------------- fp32 -> bf16 convert (x) ----------------
__global__ void cvt_bf16(const float* __restrict__ in, ushort_t* __restrict__ out, int n4) {
    int i = blockIdx.x * blockDim.x + threadIdx.x;
    if (i < n4) {
        float4 f = ((const float4*)in)[i];
        ushort4 o;
        o.x = f2bf(f.x); o.y = f2bf(f.y); o.z = f2bf(f.z); o.w = f2bf(f.w);
        ((ushort4*)out)[i] = o;
    }
}

// ---------------- fp32 [K][N] -> bf16 [N][K] transpose ----------------
__global__ void transpose_bf16(const float* __restrict__ W, ushort_t* __restrict__ WT,
                               int K, int N) {
    __shared__ ushort_t tile[32][33];
    int nb = blockIdx.x * 32, kb = blockIdx.y * 32;
    int tx = threadIdx.x, ty = threadIdx.y;
    #pragma unroll
    for (int i = ty; i < 32; i += 8)
        tile[i][tx] = f2bf(W[(size_t)(kb + i) * N + nb + tx]);
    __syncthreads();
    #pragma unroll
    for (int i = ty; i < 32; i += 8)
        WT[(size_t)(nb + i) * K + kb + tx] = tile[tx][i];
}

// ---------------- m97-style bf16 MFMA GEMM, B^T input ----------------
// C[M][N] = A[M][K] @ BT[N][K]^T + bias[N]; tiles 128x128, BK=64, 256 thr (4 waves 2x2).
template <bool OUT_BF16>
__global__ void gemm_bt(const ushort_t* __restrict__ A, const ushort_t* __restrict__ BT,
                        const float* __restrict__ bias, void* __restrict__ C,
                        int N, int K) {
    __shared__ ushort_t lsA[128 * 64];
    __shared__ ushort_t lsB[128 * 64];

    const int tid  = threadIdx.x;
    const int wave = tid >> 6;
    const int lane = tid & 63;
    const int row0 = blockIdx.x * 128;
    const int col0 = blockIdx.y * 128;
    const int wr   = (wave >> 1) * 64;
    const int wc   = (wave & 1) * 64;
    const int lrow = lane & 15;
    const int quad = lane >> 4;
    const int crow = lane >> 3;        // staging: row within 8-row chunk
    const int ccol = (lane & 7) * 8;   // staging: element col (8 bf16 = 16B)

    f32x4 acc[4][4] = {};

    for (int k0 = 0; k0 < K; k0 += 64) {
        #pragma unroll
        for (int it = 0; it < 4; ++it) {
            const int chunk = it * 4 + wave;           // 16 chunks x 1KB
            const int r = chunk * 8 + crow;
            async16(A  + (size_t)(row0 + r) * K + (k0 + ccol), lsA + chunk * 512);
            async16(BT + (size_t)(col0 + r) * K + (k0 + ccol), lsB + chunk * 512);
        }
        __syncthreads();   // drains vmcnt -> staged data visible
        #pragma unroll
        for (int kk = 0; kk < 64; kk += 32) {
            s16x8 af[4], bfr[4];
            #pragma unroll
            for (int i = 0; i < 4; ++i)
                af[i] = *(const s16x8*)(lsA + (wr + i * 16 + lrow) * 64 + kk + quad * 8);
            #pragma unroll
            for (int j = 0; j < 4; ++j)
                bfr[j] = *(const s16x8*)(lsB + (wc + j * 16 + lrow) * 64 + kk + quad * 8);
            #pragma unroll
            for (int i = 0; i < 4; ++i)
                #pragma unroll
                for (int j = 0; j < 4; ++j)
                    acc[i][j] = __builtin_amdgcn_mfma_f32_16x16x32_bf16(
                        af[i], bfr[j], acc[i][j], 0, 0, 0);
        }
        __syncthreads();
    }

    // epilogue: D mapping col=lane&15, row=quad*4+reg (m89-verified)
    #pragma unroll
    for (int i = 0; i < 4; ++i) {
        #pragma unroll
        for (int j = 0; j < 4; ++j) {
            const int col = col0 + wc + j * 16 + lrow;
            const float bv = bias[col];
            #pragma unroll
            for (int r = 0; r < 4; ++r) {
                const int row = row0 + wr + i * 16 + quad * 4 + r;
                const float v = acc[i][j][r] + bv;
                if (OUT_BF16)
                    ((ushort_t*)C)[(size_t)row * N + col] = f2bf(v);
                else
                    ((float*)C)[(size_t)row * N + col] = v;
            }
        }
    }
}

// ---------------- sparse Fenwick attention ----------------
// One wave per (b,h,t); lane = head dim d. Keys: {t} U {t - 2^k : 2^k <= t} (<=12).
__global__ void fenwick_attn(const ushort_t* __restrict__ QKV, ushort_t* __restrict__ AO) {
    const int lane = threadIdx.x & 63;
    const int wid  = blockIdx.x * 4 + (threadIdx.x >> 6);   // (b*H + h)*T + t
    const int t  = wid & (T_SEQ - 1);
    const int bh = wid >> 11;
    const int h  = bh & (HEADS - 1);
    const int b  = bh >> 4;

    const ushort_t* Qp = QKV + (size_t)b * T_SEQ * 3072;
    const int coff = h * 64 + lane;

    const float q = bf2f(Qp[(size_t)t * 3072 + coff]);

    float logit[12];
    int   pos[12];
    float mx = -1e30f;
    #pragma unroll
    for (int s = 0; s < 12; ++s) {
        const int step = (s == 0) ? 0 : (1 << (s - 1));
        const bool act = (step <= t);
        const int p = act ? (t - step) : t;
        pos[s] = p;
        const float kv = bf2f(Qp[(size_t)p * 3072 + 1024 + coff]);
        float l = q * kv;
        #pragma unroll
        for (int off = 32; off; off >>= 1) l += __shfl_xor(l, off, 64);
        l *= 0.125f;                       // Dh^-0.5, Dh=64
        logit[s] = act ? l : -1e30f;
        mx = fmaxf(mx, logit[s]);
    }
    float denom = 0.f, outv = 0.f;
    #pragma unroll
    for (int s = 0; s < 12; ++s) {
        const float w = __expf(logit[s] - mx);   // inactive -> exp(-huge) = 0
        const float vv = bf2f(Qp[(size_t)pos[s] * 3072 + 2048 + coff]);
        denom += w;
        outv  += w * vv;
    }
    AO[(size_t)(b * T_SEQ + t) * C_DIM + coff] = f2bf(outv / denom);
}

extern "C" void kernel_launch(void* const* d_in, const int* in_sizes, int n_in,
                              void* d_out, int out_size, void* d_ws, size_t ws_size,
                              hipStream_t stream) {
    const float* x      = (const float*)d_in[0];
    const float* W_qkv  = (const float*)d_in[1];
    const float* b_qkv  = (const float*)d_in[2];
    const float* W_proj = (const float*)d_in[3];
    const float* b_proj = (const float*)d_in[4];
    float* out = (float*)d_out;

    char* ws = (char*)d_ws;
    ushort_t* xb     = (ushort_t*)(ws);                       // 4096x1024 bf16
    ushort_t* WqkvT  = (ushort_t*)(ws + (size_t)8  * 1048576); // 3072x1024 bf16
    ushort_t* QKVb   = (ushort_t*)(ws + (size_t)14 * 1048576); // 4096x3072 bf16
    ushort_t* AO     = (ushort_t*)(ws + (size_t)38 * 1048576); // 4096x1024 bf16
    ushort_t* WprojT = (ushort_t*)(ws + (size_t)46 * 1048576); // 1024x1024 bf16

    cvt_bf16<<<4096, 256, 0, stream>>>(x, xb, 4096 * 1024 / 4);
    transpose_bf16<<<dim3(96, 32), dim3(32, 8), 0, stream>>>(W_qkv, WqkvT, 1024, 3072);
    transpose_bf16<<<dim3(32, 32), dim3(32, 8), 0, stream>>>(W_proj, WprojT, 1024, 1024);

    gemm_bt<true ><<<dim3(32, 24), 256, 0, stream>>>(xb, WqkvT, b_qkv, QKVb, 3072, 1024);
    fenwick_attn<<<2 * HEADS * T_SEQ / 4, 256, 0, stream>>>(QKVb, AO);
    gemm_bt<false><<<dim3(32, 8), 256, 0, stream>>>(AO, WprojT, b_proj, out, 1024, 1024);
}

// Round 2
// 164.647 us; speedup vs baseline: 1.2005x; 1.2005x over previous
//
#include <hip/hip_runtime.h>
#include <hip/hip_bf16.h>

// FenwickLogLinearAttention: B=2,T=2048,C=1024,H=16,Dh=64
// Pipeline: cvt(x)->bf16 ; W_qkv,W_proj -> transposed bf16 ([N][K]) ;
//           m97-style 128x128 MFMA GEMM (qkv, bf16 out) ;
//           sparse Fenwick attention (wave = 8 queries x 8 dim-groups) ;
//           m97-style GEMM (proj, fp32 out + bias) -> d_out.
// ws layout (bytes): xb@0 (8M) | WqkvT@8M (6M) | QKVb@14M (24M) | AO@38M (8M) | WprojT@46M (2M)

typedef unsigned short ushort_t;
typedef __attribute__((ext_vector_type(8))) short s16x8;
typedef __attribute__((ext_vector_type(4))) float f32x4;

#define T_SEQ 2048
#define C_DIM 1024
#define HEADS 16

__device__ __forceinline__ ushort_t f2bf(float f) {
    union { float f; unsigned u; } v{f};
    unsigned r = v.u + 0x7FFFu + ((v.u >> 16) & 1u);   // RNE
    return (ushort_t)(r >> 16);
}
__device__ __forceinline__ float bf2f(ushort_t u) {
    union { unsigned u; float f; } v{((unsigned)u) << 16};
    return v.f;
}

__device__ __forceinline__ void async16(const ushort_t* g, ushort_t* l) {
    __builtin_amdgcn_global_load_lds(
        (const __attribute__((address_space(1))) void*)g,
        (__attribute__((address_space(3))) void*)l, 16, 0, 0);
}

// ---------------- fp32 -> bf16 convert (x) ----------------
__global__ void cvt_bf16(const float* __restrict__ in, ushort_t* __restrict__ out, int n4) {
    int i = blockIdx.x * blockDim.x + threadIdx.x;
    if (i < n4) {
        float4 f = ((const float4*)in)[i];
        ushort4 o;
        o.x = f2bf(f.x); o.y = f2bf(f.y); o.z = f2bf(f.z); o.w = f2bf(f.w);
        ((ushort4*)out)[i] = o;
    }
}

// ---------------- fp32 [K][N] -> bf16 [N][K] transpose ----------------
__global__ void transpose_bf16(const float* __restrict__ W, ushort_t* __restrict__ WT,
                               int K, int N) {
    __shared__ ushort_t tile[32][33];
    int nb = blockIdx.x * 32, kb = blockIdx.y * 32;
    int tx = threadIdx.x, ty = threadIdx.y;
    #pragma unroll
    for (int i = ty; i < 32; i += 8)
        tile[i][tx] = f2bf(W[(size_t)(kb + i) * N + nb + tx]);
    __syncthreads();
    #pragma unroll
    for (int i = ty; i < 32; i += 8)
        WT[(size_t)(nb + i) * K + kb + tx] = tile[tx][i];
}

// ---------------- m97-style bf16 MFMA GEMM, B^T input ----------------
// C[M][N] = A[M][K] @ BT[N][K]^T + bias[N]; tiles 128x128, BK=64, 256 thr (4 waves 2x2).
template <bool OUT_BF16>
__global__ void gemm_bt(const ushort_t* __restrict__ A, const ushort_t* __restrict__ BT,
                        const float* __restrict__ bias, void* __restrict__ C,
                        int N, int K) {
    __shared__ ushort_t lsA[128 * 64];
    __shared__ ushort_t lsB[128 * 64];

    const int tid  = threadIdx.x;
    const int wave = tid >> 6;
    const int lane = tid & 63;
    const int row0 = blockIdx.x * 128;
    const int col0 = blockIdx.y * 128;
    const int wr   = (wave >> 1) * 64;
    const int wc   = (wave & 1) * 64;
    const int lrow = lane & 15;
    const int quad = lane >> 4;
    const int crow = lane >> 3;        // staging: row within 8-row chunk
    const int ccol = (lane & 7) * 8;   // staging: element col (8 bf16 = 16B)

    f32x4 acc[4][4] = {};

    for (int k0 = 0; k0 < K; k0 += 64) {
        #pragma unroll
        for (int it = 0; it < 4; ++it) {
            const int chunk = it * 4 + wave;           // 16 chunks x 1KB
            const int r = chunk * 8 + crow;
            async16(A  + (size_t)(row0 + r) * K + (k0 + ccol), lsA + chunk * 512);
            async16(BT + (size_t)(col0 + r) * K + (k0 + ccol), lsB + chunk * 512);
        }
        __syncthreads();   // drains vmcnt -> staged data visible
        #pragma unroll
        for (int kk = 0; kk < 64; kk += 32) {
            s16x8 af[4], bfr[4];
            #pragma unroll
            for (int i = 0; i < 4; ++i)
                af[i] = *(const s16x8*)(lsA + (wr + i * 16 + lrow) * 64 + kk + quad * 8);
            #pragma unroll
            for (int j = 0; j < 4; ++j)
                bfr[j] = *(const s16x8*)(lsB + (wc + j * 16 + lrow) * 64 + kk + quad * 8);
            #pragma unroll
            for (int i = 0; i < 4; ++i)
                #pragma unroll
                for (int j = 0; j < 4; ++j)
                    acc[i][j] = __builtin_amdgcn_mfma_f32_16x16x32_bf16(
                        af[i], bfr[j], acc[i][j], 0, 0, 0);
        }
        __syncthreads();
    }

    // epilogue: D mapping col=lane&15, row=quad*4+reg (m89-verified)
    #pragma unroll
    for (int i = 0; i < 4; ++i) {
        #pragma unroll
        for (int j = 0; j < 4; ++j) {
            const int col = col0 + wc + j * 16 + lrow;
            const float bv = bias[col];
            #pragma unroll
            for (int r = 0; r < 4; ++r) {
                const int row = row0 + wr + i * 16 + quad * 4 + r;
                const float v = acc[i][j][r] + bv;
                if (OUT_BF16)
                    ((ushort_t*)C)[(size_t)row * N + col] = f2bf(v);
                else
                    ((float*)C)[(size_t)row * N + col] = v;
            }
        }
    }
}

// ---------------- sparse Fenwick attention ----------------
// Wave handles 8 consecutive t for one (b,h); lane = tl*8 + g, lane owns
// dims [g*8, g*8+8) of query t0+tl via one 16B load. Keys per query:
// {t} U {t - 2^k : 2^k <= t} (<=12). All K/V loads are 1KB/wave coalesced
// (8 consecutive rows x 128B). Dot reduction: 3 shfl_xor within d-group.
__global__ void fenwick_attn(const ushort_t* __restrict__ QKV, ushort_t* __restrict__ AO) {
    const int lane = threadIdx.x & 63;
    const int wid  = blockIdx.x * 4 + (threadIdx.x >> 6);
    const int tile = wid & 255;            // 256 t-tiles of 8 per (b,h)
    const int bh   = wid >> 8;
    const int h    = bh & (HEADS - 1);
    const int b    = bh >> 4;
    const int tl   = lane >> 3;            // t within tile
    const int g    = lane & 7;             // dim group (8 dims)
    const int t    = tile * 8 + tl;

    const ushort_t* base = QKV + (size_t)(b * T_SEQ) * 3072 + h * 64 + g * 8;

    float qf[8];
    {
        s16x8 qv = *(const s16x8*)(base + (size_t)t * 3072);
        #pragma unroll
        for (int e = 0; e < 8; ++e) qf[e] = bf2f((ushort_t)qv[e]);
    }

    float logit[12];
    int   pos[12];
    float mx = -1e30f;
    #pragma unroll
    for (int s = 0; s < 12; ++s) {
        const int step = (s == 0) ? 0 : (1 << (s - 1));
        const bool act = (step <= t);
        const int p = act ? (t - step) : t;
        pos[s] = p;
        s16x8 kv = *(const s16x8*)(base + (size_t)p * 3072 + 1024);
        float l = 0.f;
        #pragma unroll
        for (int e = 0; e < 8; ++e) l = fmaf(qf[e], bf2f((ushort_t)kv[e]), l);
        l += __shfl_xor(l, 1, 64);
        l += __shfl_xor(l, 2, 64);
        l += __shfl_xor(l, 4, 64);
        l *= 0.125f;                       // Dh^-0.5, Dh=64
        logit[s] = act ? l : -1e30f;
        mx = fmaxf(mx, logit[s]);
    }

    float denom = 0.f;
    float ov[8] = {};
    #pragma unroll
    for (int s = 0; s < 12; ++s) {
        const float w = __expf(logit[s] - mx);   // inactive -> 0
        denom += w;
        s16x8 vv = *(const s16x8*)(base + (size_t)pos[s] * 3072 + 2048);
        #pragma unroll
        for (int e = 0; e < 8; ++e) ov[e] = fmaf(w, bf2f((ushort_t)vv[e]), ov[e]);
    }

    const float inv = 1.f / denom;
    s16x8 os;
    #pragma unroll
    for (int e = 0; e < 8; ++e) os[e] = (short)f2bf(ov[e] * inv);
    *(s16x8*)(AO + (size_t)(b * T_SEQ + t) * C_DIM + h * 64 + g * 8) = os;
}

extern "C" void kernel_launch(void* const* d_in, const int* in_sizes, int n_in,
                              void* d_out, int out_size, void* d_ws, size_t ws_size,
                              hipStream_t stream) {
    const float* x      = (const float*)d_in[0];
    const float* W_qkv  = (const float*)d_in[1];
    const float* b_qkv  = (const float*)d_in[2];
    const float* W_proj = (const float*)d_in[3];
    const float* b_proj = (const float*)d_in[4];
    float* out = (float*)d_out;

    char* ws = (char*)d_ws;
    ushort_t* xb     = (ushort_t*)(ws);                        // 4096x1024 bf16
    ushort_t* WqkvT  = (ushort_t*)(ws + (size_t)8  * 1048576); // 3072x1024 bf16
    ushort_t* QKVb   = (ushort_t*)(ws + (size_t)14 * 1048576); // 4096x3072 bf16
    ushort_t* AO     = (ushort_t*)(ws + (size_t)38 * 1048576); // 4096x1024 bf16
    ushort_t* WprojT = (ushort_t*)(ws + (size_t)46 * 1048576); // 1024x1024 bf16

    cvt_bf16<<<4096, 256, 0, stream>>>(x, xb, 4096 * 1024 / 4);
    transpose_bf16<<<dim3(96, 32), dim3(32, 8), 0, stream>>>(W_qkv, WqkvT, 1024, 3072);
    transpose_bf16<<<dim3(32, 32), dim3(32, 8), 0, stream>>>(W_proj, WprojT, 1024, 1024);

    gemm_bt<true ><<<dim3(32, 24), 256, 0, stream>>>(xb, WqkvT, b_qkv, QKVb, 3072, 1024);
    // 8192 waves = 2048 blocks x 4 waves; wave covers 8 queries
    fenwick_attn<<<2048, 256, 0, stream>>>(QKVb, AO);
    gemm_bt<false><<<dim3(32, 8), 256, 0, stream>>>(AO, WprojT, b_proj, out, 1024, 1024);
}

// Round 3
// 145.492 us; speedup vs baseline: 1.3586x; 1.1317x over previous
//
#include <hip/hip_runtime.h>
#include <hip/hip_bf16.h>

// FenwickLogLinearAttention: B=2,T=2048,C=1024,H=16,Dh=64
// R3: XOR-swizzled LDS k-groups in both GEMMs (kill 16-way ds_read_b128 bank
//     aliasing: row stride 128B = 32 banks exactly); proj retiled 128x64
//     (512 blocks = 2/CU); prep kernels merged into one launch.
// ws layout (bytes): xb@0 (8M) | WqkvT@8M (6M) | QKVb@14M (24M) | AO@38M (8M) | WprojT@46M (2M)

typedef unsigned short ushort_t;
typedef __attribute__((ext_vector_type(8))) short s16x8;
typedef __attribute__((ext_vector_type(4))) float f32x4;

#define T_SEQ 2048
#define C_DIM 1024
#define HEADS 16

__device__ __forceinline__ ushort_t f2bf(float f) {
    union { float f; unsigned u; } v{f};
    unsigned r = v.u + 0x7FFFu + ((v.u >> 16) & 1u);   // RNE
    return (ushort_t)(r >> 16);
}
__device__ __forceinline__ float bf2f(ushort_t u) {
    union { unsigned u; float f; } v{((unsigned)u) << 16};
    return v.f;
}

__device__ __forceinline__ void async16(const ushort_t* g, ushort_t* l) {
    __builtin_amdgcn_global_load_lds(
        (const __attribute__((address_space(1))) void*)g,
        (__attribute__((address_space(3))) void*)l, 16, 0, 0);
}

// ---------------- merged prep: cvt(x)->bf16 + two weight transposes ----------------
// blocks [0,4096): cvt 4096x1024 fp32->bf16 (float4/ushort4)
// blocks [4096,7168): W_qkv [1024][3072] -> WqkvT [3072][1024] bf16
// blocks [7168,8192): W_proj [1024][1024] -> WprojT [1024][1024] bf16
__global__ void prep(const float* __restrict__ x, ushort_t* __restrict__ xb,
                     const float* __restrict__ Wq, ushort_t* __restrict__ WqT,
                     const float* __restrict__ Wp, ushort_t* __restrict__ WpT) {
    const int bid = blockIdx.x;
    const int tid = threadIdx.x;
    if (bid < 4096) {
        const int i = bid * 256 + tid;
        float4 f = ((const float4*)x)[i];
        ushort4 o;
        o.x = f2bf(f.x); o.y = f2bf(f.y); o.z = f2bf(f.z); o.w = f2bf(f.w);
        ((ushort4*)xb)[i] = o;
    } else {
        __shared__ ushort_t tile[32][33];
        const float* W; ushort_t* WT; int N, nb, kb;
        if (bid < 7168) {
            const int tb = bid - 4096;
            W = Wq; WT = WqT; N = 3072; nb = (tb % 96) * 32; kb = (tb / 96) * 32;
        } else {
            const int tb = bid - 7168;
            W = Wp; WT = WpT; N = 1024; nb = (tb & 31) * 32; kb = (tb >> 5) * 32;
        }
        const int tx = tid & 31, ty = tid >> 5;
        #pragma unroll
        for (int i = ty; i < 32; i += 8)
            tile[i][tx] = f2bf(W[(size_t)(kb + i) * N + nb + tx]);
        __syncthreads();
        #pragma unroll
        for (int i = ty; i < 32; i += 8)
            WT[(size_t)(nb + i) * 1024 + kb + tx] = tile[tx][i];
    }
}

// ---------------- QKV GEMM: 128x128 tile, BK=64, swizzled LDS ----------------
// C[M][N] = A[M][K] @ BT[N][K]^T + bias[N], bf16 out.
// LDS layout: slot s of row r holds global k-group (s ^ (r&7)) (8 bf16/group).
__global__ void gemm_qkv(const ushort_t* __restrict__ A, const ushort_t* __restrict__ BT,
                         const float* __restrict__ bias, ushort_t* __restrict__ C,
                         int N, int K) {
    __shared__ ushort_t lsA[128 * 64];
    __shared__ ushort_t lsB[128 * 64];

    const int tid  = threadIdx.x;
    const int wave = tid >> 6;
    const int lane = tid & 63;
    const int row0 = blockIdx.x * 128;
    const int col0 = blockIdx.y * 128;
    const int wr   = (wave >> 1) * 64;
    const int wc   = (wave & 1) * 64;
    const int lrow = lane & 15;
    const int quad = lane >> 4;
    const int crow = lane >> 3;                // staging: row within 8-row chunk
    const int gcol = ((lane & 7) ^ crow) * 8;  // swizzled global k-group fetched
    const int d3   = lrow & 7;                 // read-side swizzle key

    f32x4 acc[4][4] = {};

    for (int k0 = 0; k0 < K; k0 += 64) {
        #pragma unroll
        for (int it = 0; it < 4; ++it) {
            const int chunk = it * 4 + wave;           // 16 chunks x 1KB
            const int r = chunk * 8 + crow;
            async16(A  + (size_t)(row0 + r) * K + (k0 + gcol), lsA + chunk * 512);
            async16(BT + (size_t)(col0 + r) * K + (k0 + gcol), lsB + chunk * 512);
        }
        __syncthreads();   // drains vmcnt -> staged data visible
        #pragma unroll
        for (int kk = 0; kk < 64; kk += 32) {
            const int g = (kk >> 3) + quad;            // desired k-group
            const int slot = (g ^ d3) << 3;            // swizzled LDS slot
            s16x8 af[4], bfr[4];
            #pragma unroll
            for (int i = 0; i < 4; ++i)
                af[i] = *(const s16x8*)(lsA + (wr + i * 16 + lrow) * 64 + slot);
            #pragma unroll
            for (int j = 0; j < 4; ++j)
                bfr[j] = *(const s16x8*)(lsB + (wc + j * 16 + lrow) * 64 + slot);
            #pragma unroll
            for (int i = 0; i < 4; ++i)
                #pragma unroll
                for (int j = 0; j < 4; ++j)
                    acc[i][j] = __builtin_amdgcn_mfma_f32_16x16x32_bf16(
                        af[i], bfr[j], acc[i][j], 0, 0, 0);
        }
        __syncthreads();
    }

    // D mapping: col=lane&15, row=quad*4+reg (m89-verified)
    #pragma unroll
    for (int i = 0; i < 4; ++i) {
        #pragma unroll
        for (int j = 0; j < 4; ++j) {
            const int col = col0 + wc + j * 16 + lrow;
            const float bv = bias[col];
            #pragma unroll
            for (int r = 0; r < 4; ++r) {
                const int row = row0 + wr + i * 16 + quad * 4 + r;
                C[(size_t)row * N + col] = f2bf(acc[i][j][r] + bv);
            }
        }
    }
}

// ---------------- proj GEMM: 128x64 tile, BK=64, swizzled LDS, fp32 out ----------------
// 512 blocks = 2/CU (vs 256 = 1/CU at 128x128). Wave w covers rows w*32..+32, all 64 cols.
__global__ void gemm_proj(const ushort_t* __restrict__ A, const ushort_t* __restrict__ BT,
                          const float* __restrict__ bias, float* __restrict__ C,
                          int N, int K) {
    __shared__ ushort_t lsA[128 * 64];
    __shared__ ushort_t lsB[64 * 64];

    const int tid  = threadIdx.x;
    const int wave = tid >> 6;
    const int lane = tid & 63;
    const int row0 = blockIdx.x * 128;
    const int col0 = blockIdx.y * 64;
    const int lrow = lane & 15;
    const int quad = lane >> 4;
    const int crow = lane >> 3;
    const int gcol = ((lane & 7) ^ crow) * 8;
    const int d3   = lrow & 7;

    f32x4 acc[2][4] = {};

    for (int k0 = 0; k0 < K; k0 += 64) {
        #pragma unroll
        for (int it = 0; it < 4; ++it) {
            const int chunk = it * 4 + wave;           // A: 16 chunks
            const int r = chunk * 8 + crow;
            async16(A + (size_t)(row0 + r) * K + (k0 + gcol), lsA + chunk * 512);
        }
        #pragma unroll
        for (int it = 0; it < 2; ++it) {
            const int chunk = it * 4 + wave;           // B: 8 chunks
            const int r = chunk * 8 + crow;
            async16(BT + (size_t)(col0 + r) * K + (k0 + gcol), lsB + chunk * 512);
        }
        __syncthreads();
        #pragma unroll
        for (int kk = 0; kk < 64; kk += 32) {
            const int g = (kk >> 3) + quad;
            const int slot = (g ^ d3) << 3;
            s16x8 af[2], bfr[4];
            #pragma unroll
            for (int i = 0; i < 2; ++i)
                af[i] = *(const s16x8*)(lsA + (wave * 32 + i * 16 + lrow) * 64 + slot);
            #pragma unroll
            for (int j = 0; j < 4; ++j)
                bfr[j] = *(const s16x8*)(lsB + (j * 16 + lrow) * 64 + slot);
            #pragma unroll
            for (int i = 0; i < 2; ++i)
                #pragma unroll
                for (int j = 0; j < 4; ++j)
                    acc[i][j] = __builtin_amdgcn_mfma_f32_16x16x32_bf16(
                        af[i], bfr[j], acc[i][j], 0, 0, 0);
        }
        __syncthreads();
    }

    #pragma unroll
    for (int i = 0; i < 2; ++i) {
        #pragma unroll
        for (int j = 0; j < 4; ++j) {
            const int col = col0 + j * 16 + lrow;
            const float bv = bias[col];
            #pragma unroll
            for (int r = 0; r < 4; ++r) {
                const int row = row0 + wave * 32 + i * 16 + quad * 4 + r;
                C[(size_t)row * N + col] = acc[i][j][r] + bv;
            }
        }
    }
}

// ---------------- sparse Fenwick attention ----------------
// Wave = 8 consecutive t x 8 dim-groups for one (b,h). Keys per query:
// {t} U {t - 2^k : 2^k <= t} (<=12). All K/V loads 1KB/wave coalesced.
__global__ void fenwick_attn(const ushort_t* __restrict__ QKV, ushort_t* __restrict__ AO) {
    const int lane = threadIdx.x & 63;
    const int wid  = blockIdx.x * 4 + (threadIdx.x >> 6);
    const int tile = wid & 255;
    const int bh   = wid >> 8;
    const int h    = bh & (HEADS - 1);
    const int b    = bh >> 4;
    const int tl   = lane >> 3;
    const int g    = lane & 7;
    const int t    = tile * 8 + tl;

    const ushort_t* base = QKV + (size_t)(b * T_SEQ) * 3072 + h * 64 + g * 8;

    float qf[8];
    {
        s16x8 qv = *(const s16x8*)(base + (size_t)t * 3072);
        #pragma unroll
        for (int e = 0; e < 8; ++e) qf[e] = bf2f((ushort_t)qv[e]);
    }

    float logit[12];
    int   pos[12];
    float mx = -1e30f;
    #pragma unroll
    for (int s = 0; s < 12; ++s) {
        const int step = (s == 0) ? 0 : (1 << (s - 1));
        const bool act = (step <= t);
        const int p = act ? (t - step) : t;
        pos[s] = p;
        s16x8 kv = *(const s16x8*)(base + (size_t)p * 3072 + 1024);
        float l = 0.f;
        #pragma unroll
        for (int e = 0; e < 8; ++e) l = fmaf(qf[e], bf2f((ushort_t)kv[e]), l);
        l += __shfl_xor(l, 1, 64);
        l += __shfl_xor(l, 2, 64);
        l += __shfl_xor(l, 4, 64);
        l *= 0.125f;                       // Dh^-0.5
        logit[s] = act ? l : -1e30f;
        mx = fmaxf(mx, logit[s]);
    }

    float denom = 0.f;
    float ov[8] = {};
    #pragma unroll
    for (int s = 0; s < 12; ++s) {
        const float w = __expf(logit[s] - mx);
        denom += w;
        s16x8 vv = *(const s16x8*)(base + (size_t)pos[s] * 3072 + 2048);
        #pragma unroll
        for (int e = 0; e < 8; ++e) ov[e] = fmaf(w, bf2f((ushort_t)vv[e]), ov[e]);
    }

    const float inv = 1.f / denom;
    s16x8 os;
    #pragma unroll
    for (int e = 0; e < 8; ++e) os[e] = (short)f2bf(ov[e] * inv);
    *(s16x8*)(AO + (size_t)(b * T_SEQ + t) * C_DIM + h * 64 + g * 8) = os;
}

extern "C" void kernel_launch(void* const* d_in, const int* in_sizes, int n_in,
                              void* d_out, int out_size, void* d_ws, size_t ws_size,
                              hipStream_t stream) {
    const float* x      = (const float*)d_in[0];
    const float* W_qkv  = (const float*)d_in[1];
    const float* b_qkv  = (const float*)d_in[2];
    const float* W_proj = (const float*)d_in[3];
    const float* b_proj = (const float*)d_in[4];
    float* out = (float*)d_out;

    char* ws = (char*)d_ws;
    ushort_t* xb     = (ushort_t*)(ws);                        // 4096x1024 bf16
    ushort_t* WqkvT  = (ushort_t*)(ws + (size_t)8  * 1048576); // 3072x1024 bf16
    ushort_t* QKVb   = (ushort_t*)(ws + (size_t)14 * 1048576); // 4096x3072 bf16
    ushort_t* AO     = (ushort_t*)(ws + (size_t)38 * 1048576); // 4096x1024 bf16
    ushort_t* WprojT = (ushort_t*)(ws + (size_t)46 * 1048576); // 1024x1024 bf16

    prep<<<8192, 256, 0, stream>>>(x, xb, W_qkv, WqkvT, W_proj, WprojT);
    gemm_qkv<<<dim3(32, 24), 256, 0, stream>>>(xb, WqkvT, b_qkv, QKVb, 3072, 1024);
    fenwick_attn<<<2048, 256, 0, stream>>>(QKVb, AO);
    gemm_proj<<<dim3(32, 16), 256, 0, stream>>>(AO, WprojT, b_proj, out, 1024, 1024);
}